// Round 1
// 346.220 us; speedup vs baseline: 1.0152x; 1.0152x over previous
//
#include <hip/hip_runtime.h>
#include <hip/hip_bf16.h>

typedef short s8v __attribute__((ext_vector_type(8)));
typedef float f4v __attribute__((ext_vector_type(4)));

#define MFMA_BF16 __builtin_amdgcn_mfma_f32_16x16x32_bf16

// LDS element offsets (16-bit elements). All 16B-aligned (multiple of 8 el).
// Weights keep the proven conflict-free strides (40 / 72).
constexpr int OFF_W0T  = 0;      // [64][40]  Ws0^T, k<32
constexpr int OFF_W1T  = 2560;   // [64][72]  Ws1^T
constexpr int OFF_W2T  = 7168;   // [16][72]  Ws2^T
constexpr int OFF_WC0T = 8320;   // [64][72]  Wc0^T, zero-padded k in [47,64)
constexpr int OFF_WC1T = 12928;  // [64][72]
constexpr int OFF_WC2T = 17536;  // [64][72]
constexpr int OFF_WC3T = 22144;  // [16][72]  zero rows n>=3
// H: 8 waves x [32 rows][64 cols], stride 64, chunk-XOR swizzle (bank-conflict-free
// for the b128 A-fragment reads; saves 72->64 so 8 waves fit in 2 blocks/CU).
constexpr int OFF_H    = 23296;
constexpr int SMEM_EL  = OFF_H + 8 * 2048;  // 39680 el = 79360 B -> 2 blocks/CU (16 waves/CU)

static __device__ __forceinline__ short bf2s(__hip_bfloat16 h) {
    union { __hip_bfloat16 b; short s; } u; u.b = h; return u.s;
}

__global__ __launch_bounds__(512, 4)
void rf_fused(const void* __restrict__ xv,
              const void* __restrict__ dv,
              const void* __restrict__ Ws0,
              const void* __restrict__ Ws1,
              const void* __restrict__ Ws2,
              const void* __restrict__ Wc0,
              const void* __restrict__ Wc1,
              const void* __restrict__ Wc2,
              const void* __restrict__ Wc3,
              void* __restrict__ outp,
              int npts)
{
    __shared__ __align__(16) short smem[SMEM_EL];
    __shared__ int cls_cnt;
    const int t = threadIdx.x;

    // ---- input dtype self-detection ----
    // bf16 normals: biased exponent ~[110,140] essentially always.
    // fp32-viewed-as-u16: even words are low mantissa bits -> ~12% in range.
    if (t == 0) cls_cnt = 0;
    __syncthreads();
    {
        unsigned short w = ((const unsigned short*)xv)[2 * t];
        int e = (w >> 7) & 0xFF;
        if (e >= 110 && e <= 140) atomicAdd(&cls_cnt, 1);
    }
    __syncthreads();
    const bool isbf = (cls_cnt >= 256);

    // load a weight element as bf16 bits, from either dtype
    auto ldw = [&](const void* p, int idx) -> short {
        if (isbf) return ((const short*)p)[idx];
        return bf2s(__float2bfloat16(((const float*)p)[idx]));
    };

    // ---- stage weights transposed: sW[n][k] = W[k][n] ----
    for (int i = t; i < 2048; i += 512) { int k = i >> 6, n = i & 63; smem[OFF_W0T  + n*40 + k] = ldw(Ws0, i); }
    for (int i = t; i < 4096; i += 512) { int k = i >> 6, n = i & 63; smem[OFF_W1T  + n*72 + k] = ldw(Ws1, i); }
    for (int i = t; i < 1024; i += 512) { int k = i >> 4, n = i & 15; smem[OFF_W2T  + n*72 + k] = ldw(Ws2, i); }
    for (int i = t; i < 4096; i += 512) { int n = i >> 6, k = i & 63; smem[OFF_WC0T + n*72 + k] = (k < 47) ? ldw(Wc0, k*64 + n) : (short)0; }
    for (int i = t; i < 4096; i += 512) { int k = i >> 6, n = i & 63; smem[OFF_WC1T + n*72 + k] = ldw(Wc1, i); }
    for (int i = t; i < 4096; i += 512) { int k = i >> 6, n = i & 63; smem[OFF_WC2T + n*72 + k] = ldw(Wc2, i); }
    for (int i = t; i < 1024; i += 512) { int n = i >> 6, k = i & 63; smem[OFF_WC3T + n*72 + k] = (n < 3) ? ldw(Wc3, k*3 + n) : (short)0; }
    __syncthreads();

    const int lane = t & 63;
    const int wv   = t >> 6;
    const int m16  = lane & 15;   // A-row / B-col / D-col within a 16-tile
    const int q    = lane >> 4;   // quad: A/B k-group, D row-group
    short* sH = smem + OFF_H + wv * 2048;  // per-wave [32][64] swizzled

    // swizzled H element address: chunk (16B) index XOR'd with row&7
    auto hAddr = [&](int row, int col) -> int {
        return row*64 + ((((col >> 3) ^ (row & 7))) << 3) + (col & 7);
    };

    const f4v zf = {0.f, 0.f, 0.f, 0.f};

    // fp32 fallback: 8 contiguous elements of a 32-wide row, converted to bf16 bits
    auto loadRow8f = [&](const void* p, int eoff) -> s8v {
        const float* f = (const float*)p + eoff;
        f4v f0 = *(const f4v*)f;
        f4v f1 = *(const f4v*)(f + 4);
        s8v r;
        #pragma unroll
        for (int j = 0; j < 4; j++) {
            r[j]     = bf2s(__float2bfloat16(f0[j]));
            r[j + 4] = bf2s(__float2bfloat16(f1[j]));
        }
        return r;
    };
    auto putOut = [&](int idx, float v) {
        if (isbf) ((short*)outp)[idx] = bf2s(__float2bfloat16(v));
        else      ((float*)outp)[idx] = v;
    };

    // A-frag loads from sH: A[m=m16][k=ks*32+q*8+j]  (swizzled chunk)
    auto loadAH = [&](s8v (&af)[2][2]) {
        asm volatile("" ::: "memory");   // fence vs preceding H stores
        #pragma unroll
        for (int mt = 0; mt < 2; mt++)
            #pragma unroll
            for (int ks = 0; ks < 2; ks++)
                af[mt][ks] = *(const s8v*)(sH + (mt*16 + m16)*64 + (((ks*4 + q) ^ (m16 & 7)) << 3));
    };
    // 64-wide layer: acc[mt][nt] = A(32x64) @ W(64x64)
    auto layer64 = [&](int woff, f4v (&a)[2][4], const s8v (&af)[2][2]) {
        #pragma unroll
        for (int nt = 0; nt < 4; nt++) {
            s8v b0 = *(const s8v*)(smem + woff + (nt*16 + m16)*72 + q*8);
            s8v b1 = *(const s8v*)(smem + woff + (nt*16 + m16)*72 + 32 + q*8);
            #pragma unroll
            for (int mt = 0; mt < 2; mt++)
                a[mt][nt] = MFMA_BF16(af[mt][1], b1, MFMA_BF16(af[mt][0], b0, zf, 0,0,0), 0,0,0);
        }
    };
    // relu + write 32x64 D tiles to sH (D: row = q*4+r, col = m16, per 16-tile)
    auto storeH64 = [&](const f4v (&a)[2][4]) {
        #pragma unroll
        for (int mt = 0; mt < 2; mt++)
            #pragma unroll
            for (int nt = 0; nt < 4; nt++)
                #pragma unroll
                for (int r = 0; r < 4; r++) {
                    int row = mt*16 + q*4 + r;
                    sH[row*64 + (((nt*2 + (m16 >> 3)) ^ (row & 7)) << 3) + (m16 & 7)] =
                        bf2s(__float2bfloat16(fmaxf(a[mt][nt][r], 0.f)));
                }
        asm volatile("" ::: "memory");
    };

    const int ntiles = npts / 32;
    const int tstep  = gridDim.x * 8;
    int tile = blockIdx.x * 8 + wv;

    // ---- software-pipelined x/d loads (bf16 fast path) ----
    s8v xr[2], dr[2];
    if (isbf && tile < ntiles) {
        #pragma unroll
        for (int mt = 0; mt < 2; mt++) {
            const int off = (tile*32 + mt*16 + m16)*32 + q*8;
            xr[mt] = *(const s8v*)((const short*)xv + off);
            dr[mt] = *(const s8v*)((const short*)dv + off);
        }
    }

    for (; tile < ntiles; tile += tstep) {
        const int r0  = tile * 32;
        const int nxt = tile + tstep;

        // issue next tile's global loads now; they complete under this tile's compute
        s8v xrn[2], drn[2];
        if (isbf && nxt < ntiles) {
            #pragma unroll
            for (int mt = 0; mt < 2; mt++) {
                const int off = (nxt*32 + mt*16 + m16)*32 + q*8;
                xrn[mt] = *(const s8v*)((const short*)xv + off);
                drn[mt] = *(const s8v*)((const short*)dv + off);
            }
        }

        s8v xa[2], da[2];
        if (isbf) {
            xa[0] = xr[0]; xa[1] = xr[1];
            da[0] = dr[0]; da[1] = dr[1];
        } else {
            #pragma unroll
            for (int mt = 0; mt < 2; mt++) {
                const int off = (r0 + mt*16 + m16)*32 + q*8;
                xa[mt] = loadRow8f(xv, off);
                da[mt] = loadRow8f(dv, off);
            }
        }

        f4v acc[2][4];

        // ---------------- sigma net ----------------
        // L1: X(32x32) @ Ws0(32x64)
        #pragma unroll
        for (int nt = 0; nt < 4; nt++) {
            s8v b = *(const s8v*)(smem + OFF_W0T + (nt*16 + m16)*40 + q*8);
            #pragma unroll
            for (int mt = 0; mt < 2; mt++)
                acc[mt][nt] = MFMA_BF16(xa[mt], b, zf, 0,0,0);
        }
        storeH64(acc);   // H1

        // L2: H1 @ Ws1
        s8v a2[2][2];
        loadAH(a2);
        layer64(OFF_W1T, acc, a2);
        storeH64(acc);   // H2

        // L3: H2 @ Ws2 (64x16), one n-tile
        s8v a3[2][2];
        loadAH(a3);
        s8v c0 = *(const s8v*)(smem + OFF_W2T + m16*72 + q*8);
        s8v c1 = *(const s8v*)(smem + OFF_W2T + m16*72 + 32 + q*8);
        f4v acc3[2];
        #pragma unroll
        for (int mt = 0; mt < 2; mt++)
            acc3[mt] = MFMA_BF16(a3[mt][1], c1, MFMA_BF16(a3[mt][0], c0, zf, 0,0,0), 0,0,0);

        // sigma out (col 0) + geo (cols 1..15 -> sH cols 0..14, col 15 zeroed)
        #pragma unroll
        for (int mt = 0; mt < 2; mt++)
            #pragma unroll
            for (int r = 0; r < 4; r++) {
                float v = fmaxf(acc3[mt][r], 0.f);
                int row = mt*16 + q*4 + r;
                if (m16 == 0) {
                    putOut(3*npts + r0 + row, v);
                    sH[hAddr(row, 15)] = 0;
                } else {
                    sH[hAddr(row, m16 - 1)] = bf2s(__float2bfloat16(v));
                }
            }
        asm volatile("" ::: "memory");

        // ---------------- color net ----------------
        // Hc0: [d | geo] K=64: k<32 = d, k in [32,47) = geo, k>=47 hits zero
        // weight rows (stale finite sH cols 16..31 contribute exactly 0)
        s8v ga[2];
        #pragma unroll
        for (int mt = 0; mt < 2; mt++)
            ga[mt] = *(const s8v*)(sH + (mt*16 + m16)*64 + ((q ^ (m16 & 7)) << 3));
        #pragma unroll
        for (int nt = 0; nt < 4; nt++) {
            s8v b0 = *(const s8v*)(smem + OFF_WC0T + (nt*16 + m16)*72 + q*8);
            s8v b1 = *(const s8v*)(smem + OFF_WC0T + (nt*16 + m16)*72 + 32 + q*8);
            #pragma unroll
            for (int mt = 0; mt < 2; mt++)
                acc[mt][nt] = MFMA_BF16(ga[mt], b1, MFMA_BF16(da[mt], b0, zf, 0,0,0), 0,0,0);
        }
        storeH64(acc);   // H4

        // Wc1
        s8v a5[2][2];
        loadAH(a5);
        layer64(OFF_WC1T, acc, a5);
        storeH64(acc);   // H5

        // Wc2
        s8v a6[2][2];
        loadAH(a6);
        layer64(OFF_WC2T, acc, a6);
        storeH64(acc);   // H6

        // Wc3 (64x3, padded to 16): no relu, sigmoid, write color
        s8v a7[2][2];
        loadAH(a7);
        s8v e0 = *(const s8v*)(smem + OFF_WC3T + m16*72 + q*8);
        s8v e1 = *(const s8v*)(smem + OFF_WC3T + m16*72 + 32 + q*8);
        f4v acc7[2];
        #pragma unroll
        for (int mt = 0; mt < 2; mt++)
            acc7[mt] = MFMA_BF16(a7[mt][1], e1, MFMA_BF16(a7[mt][0], e0, zf, 0,0,0), 0,0,0);

        if (m16 < 3) {
            #pragma unroll
            for (int mt = 0; mt < 2; mt++)
                #pragma unroll
                for (int r = 0; r < 4; r++) {
                    float v  = acc7[mt][r];
                    float sg = 1.0f / (1.0f + __expf(-v));
                    putOut((r0 + mt*16 + q*4 + r)*3 + m16, sg);
                }
        }

        // rotate prefetch registers
        if (isbf) {
            xr[0] = xrn[0]; xr[1] = xrn[1];
            dr[0] = drn[0]; dr[1] = drn[1];
        }
    }
}

extern "C" void kernel_launch(void* const* d_in, const int* in_sizes, int n_in,
                              void* d_out, int out_size, void* d_ws, size_t ws_size,
                              hipStream_t stream) {
    const int npts = in_sizes[0] / 32;
    // 512 blocks x 512 thr = 8 waves/block; 79.4 KB LDS -> 2 blocks/CU resident
    // = 16 waves/CU (4 waves/SIMD), all 512 blocks co-resident, 8 tiles/wave.
    rf_fused<<<512, 512, 0, stream>>>(d_in[0], d_in[1], d_in[2], d_in[3], d_in[4],
                                      d_in[5], d_in[6], d_in[7], d_in[8],
                                      d_out, npts);
}

// Round 2
// 314.891 us; speedup vs baseline: 1.1162x; 1.0995x over previous
//
#include <hip/hip_runtime.h>
#include <hip/hip_bf16.h>

typedef short s8v __attribute__((ext_vector_type(8)));
typedef float f4v __attribute__((ext_vector_type(4)));

#define MFMA_BF16 __builtin_amdgcn_mfma_f32_16x16x32_bf16

// LDS element offsets (16-bit elements). All 16B-aligned.
// Weights keep the proven conflict-free strides (40 / 72); read as A-operand now.
constexpr int OFF_W0T  = 0;      // [64][40]  Ws0^T, k<32
constexpr int OFF_W1T  = 2560;   // [64][72]  Ws1^T
constexpr int OFF_W2T  = 7168;   // [16][72]  Ws2^T
constexpr int OFF_WC0T = 8320;   // [64][72]  Wc0^T, zero-padded k in [47,64)
constexpr int OFF_WC1T = 12928;  // [64][72]
constexpr int OFF_WC2T = 17536;  // [64][72]
constexpr int OFF_WC3T = 22144;  // [16][72]  zero rows n>=3
// Geo staging: 8 waves x [32 points][32 feats] (upper 16 feats stay zero).
constexpr int OFF_G    = 23168;
constexpr int SMEM_EL  = OFF_G + 8 * 1024;  // 31360 el = 62720 B -> 2 blocks/CU

static __device__ __forceinline__ short bf2s(__hip_bfloat16 h) {
    union { __hip_bfloat16 b; short s; } u; u.b = h; return u.s;
}

__global__ __launch_bounds__(512, 4)
void rf_fused(const void* __restrict__ xv,
              const void* __restrict__ dv,
              const void* __restrict__ Ws0,
              const void* __restrict__ Ws1,
              const void* __restrict__ Ws2,
              const void* __restrict__ Wc0,
              const void* __restrict__ Wc1,
              const void* __restrict__ Wc2,
              const void* __restrict__ Wc3,
              void* __restrict__ outp,
              int npts)
{
    __shared__ __align__(16) short smem[SMEM_EL];
    __shared__ int cls_cnt;
    const int t = threadIdx.x;

    // ---- input dtype self-detection ----
    if (t == 0) cls_cnt = 0;
    __syncthreads();
    {
        unsigned short w = ((const unsigned short*)xv)[2 * t];
        int e = (w >> 7) & 0xFF;
        if (e >= 110 && e <= 140) atomicAdd(&cls_cnt, 1);
    }
    __syncthreads();
    const bool isbf = (cls_cnt >= 256);

    auto ldw = [&](const void* p, int idx) -> short {
        if (isbf) return ((const short*)p)[idx];
        return bf2s(__float2bfloat16(((const float*)p)[idx]));
    };

    // ---- stage weights transposed: sW[n][k] = W[k][n] ----
    for (int i = t; i < 2048; i += 512) { int k = i >> 6, n = i & 63; smem[OFF_W0T  + n*40 + k] = ldw(Ws0, i); }
    for (int i = t; i < 4096; i += 512) { int k = i >> 6, n = i & 63; smem[OFF_W1T  + n*72 + k] = ldw(Ws1, i); }
    for (int i = t; i < 1024; i += 512) { int k = i >> 4, n = i & 15; smem[OFF_W2T  + n*72 + k] = ldw(Ws2, i); }
    for (int i = t; i < 4096; i += 512) { int n = i >> 6, k = i & 63; smem[OFF_WC0T + n*72 + k] = (k < 47) ? ldw(Wc0, k*64 + n) : (short)0; }
    for (int i = t; i < 4096; i += 512) { int k = i >> 6, n = i & 63; smem[OFF_WC1T + n*72 + k] = ldw(Wc1, i); }
    for (int i = t; i < 4096; i += 512) { int k = i >> 6, n = i & 63; smem[OFF_WC2T + n*72 + k] = ldw(Wc2, i); }
    for (int i = t; i < 1024; i += 512) { int n = i >> 6, k = i & 63; smem[OFF_WC3T + n*72 + k] = (n < 3) ? ldw(Wc3, k*3 + n) : (short)0; }
    // zero geo staging once (upper half stays zero; lower half rewritten per tile)
    for (int i = t; i < 8192; i += 512) smem[OFF_G + i] = 0;
    __syncthreads();

    const int lane = t & 63;
    const int wv   = t >> 6;
    const int m16  = lane & 15;   // point within 16-tile (B/D column)
    const int q    = lane >> 4;   // quad: k-group for A/B, feature-row-group for D
    short* sG = smem + OFF_G + wv * 1024;  // per-wave [32 points][32 feats]

    const f4v zf = {0.f, 0.f, 0.f, 0.f};

    auto loadRow8f = [&](const void* p, int eoff) -> s8v {
        const float* f = (const float*)p + eoff;
        f4v f0 = *(const f4v*)f;
        f4v f1 = *(const f4v*)(f + 4);
        s8v r;
        #pragma unroll
        for (int j = 0; j < 4; j++) {
            r[j]     = bf2s(__float2bfloat16(f0[j]));
            r[j + 4] = bf2s(__float2bfloat16(f1[j]));
        }
        return r;
    };
    auto putOut = [&](int idx, float v) {
        if (isbf) ((short*)outp)[idx] = bf2s(__float2bfloat16(v));
        else      ((float*)outp)[idx] = v;
    };

    // ---- in-register feature redistribution (replaces the LDS H round-trip) ----
    // Input: a[kt][r] = relu'd H^T output, feature f = kt*16 + q*4 + r, one point/lane.
    // Output: fr[kc] = B-fragment, element j = bf16 of feature kc*32 + q*8 + j.
    // Route via u32 index g=f>>1 (bits g4..g0): quad moves (g2,g1) -> (g3,g2):
    //   permlane32_swap transposes (lane-bit5, slot-bit g3);
    //   permlane16_swap transposes (lane-bit4, slot-bit g2).
    auto redist = [&](const f4v (&a)[4], s8v (&fr)[2]) {
        unsigned int P[4][2];
        #pragma unroll
        for (int kt = 0; kt < 4; kt++)
            #pragma unroll
            for (int rp = 0; rp < 2; rp++) {
                float lo = fmaxf(a[kt][2*rp],     0.f);
                float hi = fmaxf(a[kt][2*rp + 1], 0.f);
                union { __hip_bfloat162 b; unsigned int u; } cu;
                cu.b = __float22bfloat162_rn(float2{lo, hi});
                P[kt][rp] = cu.u;
            }
        #pragma unroll
        for (int a2 = 0; a2 < 2; a2++)
            #pragma unroll
            for (int rp = 0; rp < 2; rp++) {
                asm("v_permlane32_swap_b32 %0, %1" : "+v"(P[2*a2][rp]), "+v"(P[2*a2+1][rp]));
                asm("v_permlane16_swap_b32 %0, %1" : "+v"(P[2*a2][rp]), "+v"(P[2*a2+1][rp]));
            }
        #pragma unroll
        for (int kc = 0; kc < 2; kc++) {
            union { unsigned int u[4]; s8v v; } fu;
            fu.u[0] = P[2*kc][0];     fu.u[1] = P[2*kc][1];
            fu.u[2] = P[2*kc + 1][0]; fu.u[3] = P[2*kc + 1][1];
            fr[kc] = fu.v;
        }
    };

    // 64-out transposed layer: acc[pt][kt] = W^T(A, from LDS) @ H^T(B, in regs)
    auto layerT = [&](int woff, const s8v (&bf)[2][2], f4v (&out)[2][4]) {
        #pragma unroll
        for (int kt = 0; kt < 4; kt++) {
            s8v a0 = *(const s8v*)(smem + woff + (kt*16 + m16)*72 + q*8);
            s8v a1 = *(const s8v*)(smem + woff + (kt*16 + m16)*72 + 32 + q*8);
            #pragma unroll
            for (int pt = 0; pt < 2; pt++)
                out[pt][kt] = MFMA_BF16(a1, bf[pt][1], MFMA_BF16(a0, bf[pt][0], zf, 0,0,0), 0,0,0);
        }
    };

    const int ntiles = npts / 32;
    const int tstep  = gridDim.x * 8;
    int tile = blockIdx.x * 8 + wv;

    // ---- software-pipelined x/d loads (bf16 fast path) ----
    s8v xr[2], dr[2];
    if (isbf && tile < ntiles) {
        #pragma unroll
        for (int pt = 0; pt < 2; pt++) {
            const int off = (tile*32 + pt*16 + m16)*32 + q*8;
            xr[pt] = *(const s8v*)((const short*)xv + off);
            dr[pt] = *(const s8v*)((const short*)dv + off);
        }
    }

    for (; tile < ntiles; tile += tstep) {
        const int r0  = tile * 32;
        const int nxt = tile + tstep;

        s8v xrn[2], drn[2];
        if (isbf && nxt < ntiles) {
            #pragma unroll
            for (int pt = 0; pt < 2; pt++) {
                const int off = (nxt*32 + pt*16 + m16)*32 + q*8;
                xrn[pt] = *(const s8v*)((const short*)xv + off);
                drn[pt] = *(const s8v*)((const short*)dv + off);
            }
        }

        s8v xb[2], db[2];
        if (isbf) {
            xb[0] = xr[0]; xb[1] = xr[1];
            db[0] = dr[0]; db[1] = dr[1];
        } else {
            #pragma unroll
            for (int pt = 0; pt < 2; pt++) {
                const int off = (r0 + pt*16 + m16)*32 + q*8;
                xb[pt] = loadRow8f(xv, off);
                db[pt] = loadRow8f(dv, off);
            }
        }

        f4v acc[2][4];
        s8v bf[2][2];

        // ---------------- sigma net (all transposed) ----------------
        // L1: H1^T = Ws0^T(64x32) @ X^T(32x32)
        #pragma unroll
        for (int kt = 0; kt < 4; kt++) {
            s8v a0 = *(const s8v*)(smem + OFF_W0T + (kt*16 + m16)*40 + q*8);
            #pragma unroll
            for (int pt = 0; pt < 2; pt++)
                acc[pt][kt] = MFMA_BF16(a0, xb[pt], zf, 0,0,0);
        }
        #pragma unroll
        for (int pt = 0; pt < 2; pt++) redist(acc[pt], bf[pt]);

        // L2: H2^T = Ws1^T @ H1^T
        layerT(OFF_W1T, bf, acc);
        #pragma unroll
        for (int pt = 0; pt < 2; pt++) redist(acc[pt], bf[pt]);

        // L3: H3^T(16x32) = Ws2^T(16x64) @ H2^T
        f4v s3[2];
        {
            s8v c0 = *(const s8v*)(smem + OFF_W2T + m16*72 + q*8);
            s8v c1 = *(const s8v*)(smem + OFF_W2T + m16*72 + 32 + q*8);
            #pragma unroll
            for (int pt = 0; pt < 2; pt++)
                s3[pt] = MFMA_BF16(c1, bf[pt][1], MFMA_BF16(c0, bf[pt][0], zf, 0,0,0), 0,0,0);
        }

        // sigma out (feature 0) + geo (features 1..15 -> sG[point][f-1], sG[15]=0)
        #pragma unroll
        for (int pt = 0; pt < 2; pt++) {
            const int point = pt*16 + m16;
            #pragma unroll
            for (int r = 0; r < 4; r++) {
                float v = fmaxf(s3[pt][r], 0.f);
                if (q*4 + r == 0) {
                    putOut(3*npts + r0 + point, v);
                    sG[point*32 + 15] = 0;
                } else {
                    sG[point*32 + q*4 + r - 1] = bf2s(__float2bfloat16(v));
                }
            }
        }
        asm volatile("" ::: "memory");

        // geo B-fragments: k in [32,64): sG[point][q*8+j] (zeros beyond feat 14)
        s8v gb[2];
        #pragma unroll
        for (int pt = 0; pt < 2; pt++)
            gb[pt] = *(const s8v*)(sG + (pt*16 + m16)*32 + q*8);
        asm volatile("" ::: "memory");

        // ---------------- color net ----------------
        // C0: Hc1^T = Wc0^T @ [d | geo]^T
        #pragma unroll
        for (int pt = 0; pt < 2; pt++) { bf[pt][0] = db[pt]; bf[pt][1] = gb[pt]; }
        layerT(OFF_WC0T, bf, acc);
        #pragma unroll
        for (int pt = 0; pt < 2; pt++) redist(acc[pt], bf[pt]);

        // C1
        layerT(OFF_WC1T, bf, acc);
        #pragma unroll
        for (int pt = 0; pt < 2; pt++) redist(acc[pt], bf[pt]);

        // C2
        layerT(OFF_WC2T, bf, acc);
        #pragma unroll
        for (int pt = 0; pt < 2; pt++) redist(acc[pt], bf[pt]);

        // C3: RGB^T(16x32) = Wc3^T(16x64) @ Hc3^T ; features 0..2 valid (q==0 lanes)
        f4v c7[2];
        {
            s8v e0 = *(const s8v*)(smem + OFF_WC3T + m16*72 + q*8);
            s8v e1 = *(const s8v*)(smem + OFF_WC3T + m16*72 + 32 + q*8);
            #pragma unroll
            for (int pt = 0; pt < 2; pt++)
                c7[pt] = MFMA_BF16(e1, bf[pt][1], MFMA_BF16(e0, bf[pt][0], zf, 0,0,0), 0,0,0);
        }
        if (q == 0) {
            #pragma unroll
            for (int pt = 0; pt < 2; pt++) {
                const int base = (r0 + pt*16 + m16) * 3;
                #pragma unroll
                for (int r = 0; r < 3; r++) {
                    float v  = c7[pt][r];
                    float sg = 1.0f / (1.0f + __expf(-v));
                    putOut(base + r, sg);
                }
            }
        }

        // rotate prefetch registers
        if (isbf) {
            xr[0] = xrn[0]; xr[1] = xrn[1];
            dr[0] = drn[0]; dr[1] = drn[1];
        }
    }
}

extern "C" void kernel_launch(void* const* d_in, const int* in_sizes, int n_in,
                              void* d_out, int out_size, void* d_ws, size_t ws_size,
                              hipStream_t stream) {
    const int npts = in_sizes[0] / 32;
    // 512 blocks x 512 thr; 62.7 KB LDS -> 2 blocks/CU, 16 waves/CU, 8 tiles/wave
    rf_fused<<<512, 512, 0, stream>>>(d_in[0], d_in[1], d_in[2], d_in[3], d_in[4],
                                      d_in[5], d_in[6], d_in[7], d_in[8],
                                      d_out, npts);
}